// Round 11
// baseline (105.205 us; speedup 1.0000x reference)
//
#include <hip/hip_runtime.h>

#define NROWS 32768
#define NE    1024
#define ED    64
#define RPW   4                // rows per wave
#define NW    4                // waves per block
#define RPB   (RPW * NW)       // 16 rows per block

typedef float4 f4;

// ---------------------------------------------------------------------------
// Prep: eTi[k4][code] = f4(cb[code][4k4..4k4+3]) (k4-blocked transpose,
// coalesced writes) + ssq[code] with numpy pairwise-8 op order.
// ---------------------------------------------------------------------------
__global__ void vq_prep(const float* __restrict__ cb, f4* __restrict__ eTi,
                        float* __restrict__ ssq)
{
    int j = blockIdx.x * blockDim.x + threadIdx.x;   // 0..1023 code id
    const f4* crow = (const f4*)(cb + (size_t)j * ED);
    f4 v[16];
#pragma unroll
    for (int i = 0; i < 16; ++i) v[i] = crow[i];
    {
#pragma clang fp contract(off)
        float r0 = v[0].x*v[0].x, r1 = v[0].y*v[0].y;
        float r2 = v[0].z*v[0].z, r3 = v[0].w*v[0].w;
        float r4 = v[1].x*v[1].x, r5 = v[1].y*v[1].y;
        float r6 = v[1].z*v[1].z, r7 = v[1].w*v[1].w;
#pragma unroll
        for (int q = 2; q < 16; q += 2) {
            r0 += v[q].x*v[q].x;     r1 += v[q].y*v[q].y;
            r2 += v[q].z*v[q].z;     r3 += v[q].w*v[q].w;
            r4 += v[q+1].x*v[q+1].x; r5 += v[q+1].y*v[q+1].y;
            r6 += v[q+1].z*v[q+1].z; r7 += v[q+1].w*v[q+1].w;
        }
        ssq[j] = ((r0+r1)+(r2+r3)) + ((r4+r5)+(r6+r7));
    }
#pragma unroll
    for (int k4 = 0; k4 < 16; ++k4) eTi[(size_t)k4 * NE + j] = v[k4];
}

// ---------------------------------------------------------------------------
// Main: NO LDS staging, NO barriers in the scan, counters split cleanly:
//   e: coalesced global_load_dwordx4 from eTi (vmcnt, in-order, prefetchable)
//   z: wave-uniform s_load_dwordx4 (lgkmcnt carries ONLY SMEM -> no DS mixing)
//  - 2048 blocks x 256 thr; block = 16 rows; wave = 4 rows (disjoint).
//  - per (g, k4): 1 e-load + 4 z s_loads + 16 FMAs; ~50 VGPR live -> fits
//    the 64-reg cap of (256,8) without spill.
// Numerics identical per row to passing r10: cn/ssq numpy pairwise-8;
// dot ascending-k single-acc fmaf; d = fl(fl(cn+ssq)-2*acc); first-index
// argmin (strict < over ascending g per lane, lex (d,idx) butterfly).
// ---------------------------------------------------------------------------
__global__ __launch_bounds__(256, 8)
void vq_main(const float* __restrict__ z, const float* __restrict__ cb,
             const f4* __restrict__ eTi, const float* __restrict__ ssq,
             float* __restrict__ out, float* __restrict__ partials)
{
    __shared__ int   idxsh[RPB];
    __shared__ float redsh[NW];

    const int tid  = threadIdx.x;
    const int lane = tid & 63;
    const int w    = tid >> 6;                       // wave 0..3
    const int w_u  = __builtin_amdgcn_readfirstlane(w);
    const int rowbase = blockIdx.x * RPB;

    const float* zw = z + (size_t)(rowbase + w_u * RPW) * ED;  // scalar base

    // ---- row norms for this wave's 4 rows, numpy pairwise-8 ----
    float cn[RPW];
    {
        const int rl = (lane >> 3) & 3;      // row within wave's 4 (dup hi lanes)
        const int jj = lane & 7;             // accumulator index
        const float* zr = zw + (size_t)rl * ED;
        float a;
        {
#pragma clang fp contract(off)
            a = 0.f;
#pragma unroll
            for (int i = 0; i < 8; ++i) { float v = zr[8*i + jj]; a += v*v; }
        }
        a += __shfl_xor(a, 1);
        a += __shfl_xor(a, 2);
        a += __shfl_xor(a, 4);
#pragma unroll
        for (int r = 0; r < RPW; ++r) cn[r] = __shfl(a, r * 8);
    }

    float bestv[RPW];
    int   besti[RPW];
#pragma unroll
    for (int r = 0; r < RPW; ++r) { bestv[r] = INFINITY; besti[r] = 0; }

    // ---- scan all 1024 codes in 16 groups of 64 (code = g*64 + lane) ----
    for (int g = 0; g < 16; ++g) {
        const int c = g * 64 + lane;                 // this lane's code
        const float sq = ssq[c];                     // coalesced, L2-hot

        float a0 = 0.f, a1 = 0.f, a2 = 0.f, a3 = 0.f;

#pragma unroll 4
        for (int k4 = 0; k4 < 16; ++k4) {
            f4 e  = eTi[(size_t)k4 * NE + c];        // global dwordx4 (vmcnt)
            f4 z0 = *(const f4*)(zw + 0*ED + 4*k4);  // s_load_dwordx4 (SMEM)
            f4 z1 = *(const f4*)(zw + 1*ED + 4*k4);
            f4 z2 = *(const f4*)(zw + 2*ED + 4*k4);
            f4 z3 = *(const f4*)(zw + 3*ED + 4*k4);
            a0 = fmaf(e.x, z0.x, a0); a0 = fmaf(e.y, z0.y, a0);
            a0 = fmaf(e.z, z0.z, a0); a0 = fmaf(e.w, z0.w, a0);
            a1 = fmaf(e.x, z1.x, a1); a1 = fmaf(e.y, z1.y, a1);
            a1 = fmaf(e.z, z1.z, a1); a1 = fmaf(e.w, z1.w, a1);
            a2 = fmaf(e.x, z2.x, a2); a2 = fmaf(e.y, z2.y, a2);
            a2 = fmaf(e.z, z2.z, a2); a2 = fmaf(e.w, z2.w, a2);
            a3 = fmaf(e.x, z3.x, a3); a3 = fmaf(e.y, z3.y, a3);
            a3 = fmaf(e.z, z3.z, a3); a3 = fmaf(e.w, z3.w, a3);
        }

        {
#pragma clang fp contract(off)
            float d0 = (cn[0] + sq) - 2.0f * a0;     // 2*acc exact
            float d1 = (cn[1] + sq) - 2.0f * a1;
            float d2 = (cn[2] + sq) - 2.0f * a2;
            float d3 = (cn[3] + sq) - 2.0f * a3;
            if (d0 < bestv[0]) { bestv[0] = d0; besti[0] = c; }
            if (d1 < bestv[1]) { bestv[1] = d1; besti[1] = c; }
            if (d2 < bestv[2]) { bestv[2] = d2; besti[2] = c; }
            if (d3 < bestv[3]) { bestv[3] = d3; besti[3] = c; }
        }
    }

    // ---- cross-lane lexicographic (val, idx) argmin per row ----
#pragma unroll
    for (int r = 0; r < RPW; ++r) {
        float v = bestv[r];
        int   i = besti[r];
#pragma unroll
        for (int m = 1; m < 64; m <<= 1) {
            float ov = __shfl_xor(v, m);
            int   oi = __shfl_xor(i, m);
            if (ov < v || (ov == v && oi < i)) { v = ov; i = oi; }
        }
        if (lane == 0) idxsh[w * RPW + r] = i & (NE - 1);
    }
    __syncthreads();

    // ---- uniform coalesced idx store (f32) ----
    if (tid < RPB)
        out[(size_t)NROWS * ED + rowbase + tid] = (float)idxsh[tid];

    // ---- epilogue: thread -> (row = tid>>4, f4-col = tid&15) ----
    const int erow = tid >> 4;
    const int q4   = tid & 15;
    const int gi   = idxsh[erow];
    f4 e  = *(const f4*)(cb + (size_t)gi * ED + q4 * 4);
    f4 zz = *(const f4*)(z + (size_t)(rowbase + erow) * ED + q4 * 4);
    float lp;
    f4 o;
    {
#pragma clang fp contract(off)
        float d0 = e.x - zz.x; o.x = zz.x + d0;
        float d1 = e.y - zz.y; o.y = zz.y + d1;
        float d2 = e.z - zz.z; o.z = zz.z + d2;
        float d3 = e.w - zz.w; o.w = zz.w + d3;
        lp = ((d0*d0 + d1*d1) + (d2*d2 + d3*d3));
    }
    *(f4*)(out + (size_t)(rowbase + erow) * ED + q4 * 4) = o;

    // ---- deterministic loss partial ----
#pragma unroll
    for (int m = 1; m < 64; m <<= 1) lp += __shfl_xor(lp, m);
    if (lane == 0) redsh[w] = lp;
    __syncthreads();
    if (tid == 0)
        partials[blockIdx.x] = (redsh[0] + redsh[1]) + (redsh[2] + redsh[3]);
}

// ---------------------------------------------------------------------------
// Finalize: deterministic tree-sum of 2048 partials -> loss scalar (f32)
// ---------------------------------------------------------------------------
__global__ void vq_finalize(const float* __restrict__ partials,
                            float* __restrict__ out)
{
    __shared__ float red[256];
    int t = threadIdx.x;
    float a = (partials[t]        + partials[t + 256])
            + (partials[t + 512]  + partials[t + 768]);
    float b = (partials[t + 1024] + partials[t + 1280])
            + (partials[t + 1536] + partials[t + 1792]);
    red[t] = a + b;
    __syncthreads();
    for (int m = 128; m > 0; m >>= 1) {
        if (t < m) red[t] += red[t + m];
        __syncthreads();
    }
    if (t == 0) {
        float mean = red[0] / (float)((size_t)NROWS * ED);
        out[(size_t)NROWS * ED + NROWS] = mean + 0.25f * mean;  // (1+BETA)*mean
    }
}

extern "C" void kernel_launch(void* const* d_in, const int* in_sizes, int n_in,
                              void* d_out, int out_size, void* d_ws, size_t ws_size,
                              hipStream_t stream)
{
    (void)in_sizes; (void)n_in; (void)out_size; (void)ws_size;
    const float* z  = (const float*)d_in[0];
    const float* cb = (const float*)d_in[1];
    float* out = (float*)d_out;

    f4*    eTi      = (f4*)d_ws;                     // 16*1024 f4 = 256 KB
    float* ssq      = (float*)(eTi + 16 * NE);       // 1024 f32
    float* partials = ssq + NE;                      // 2048 f32

    vq_prep<<<4, 256, 0, stream>>>(cb, eTi, ssq);
    vq_main<<<2048, 256, 0, stream>>>(z, cb, eTi, ssq, out, partials);
    vq_finalize<<<1, 256, 0, stream>>>(partials, out);
}